// Round 5
// baseline (229.556 us; speedup 1.0000x reference)
//
#include <hip/hip_runtime.h>

typedef _Float16 half8  __attribute__((ext_vector_type(8)));
typedef _Float16 half4v __attribute__((ext_vector_type(4)));
typedef _Float16 half2v __attribute__((ext_vector_type(2)));
typedef float    floatx4 __attribute__((ext_vector_type(4)));
typedef float    float2v __attribute__((ext_vector_type(2)));

static constexpr float INV2PI = 0.15915494309189535f;  // fold rad->rev into weights
static constexpr float RLOG   = 3.82843f;

// act(a) with a in revolutions: x0 = 0.5+0.5cos -> two logistic iters.
// Algebra: x0(1-x0) = 0.25 - 0.25 c^2 = p;  out = R^2 * p * (1 - R*p).
__device__ __forceinline__ float act_rev(float a) {
    float c = __builtin_amdgcn_cosf(a);
    float qq = c * c;
    float p = __builtin_fmaf(qq, -0.25f, 0.25f);
    float w = __builtin_fmaf(p, -RLOG, 1.0f);
    return (RLOG * RLOG * p) * w;
}

// Vectorized over 4 accumulator values -> 4 packed f16 (cvt_pkrtz).
__device__ __forceinline__ half4v act4(floatx4 a) {
    float2v c0 = { __builtin_amdgcn_cosf(a[0]), __builtin_amdgcn_cosf(a[1]) };
    float2v c1 = { __builtin_amdgcn_cosf(a[2]), __builtin_amdgcn_cosf(a[3]) };
    float2v q0 = c0 * c0, q1 = c1 * c1;
    float2v p0 = __builtin_elementwise_fma(q0, (float2v)(-0.25f), (float2v)(0.25f));
    float2v p1 = __builtin_elementwise_fma(q1, (float2v)(-0.25f), (float2v)(0.25f));
    float2v w0 = __builtin_elementwise_fma(p0, (float2v)(-RLOG), (float2v)(1.0f));
    float2v w1 = __builtin_elementwise_fma(p1, (float2v)(-RLOG), (float2v)(1.0f));
    float2v u0 = p0 * (RLOG * RLOG), u1 = p1 * (RLOG * RLOG);
    float2v h0 = u0 * w0, h1 = u1 * w1;
    half2v lo = __builtin_bit_cast(half2v, __builtin_amdgcn_cvt_pkrtz(h0.x, h0.y));
    half2v hi = __builtin_bit_cast(half2v, __builtin_amdgcn_cvt_pkrtz(h1.x, h1.y));
    return __builtin_shufflevector(lo, hi, 0, 1, 2, 3);
}

__device__ __forceinline__ half8 cat(half4v a, half4v b) {
    return __builtin_shufflevector(a, b, 0, 1, 2, 3, 4, 5, 6, 7);
}

// Register-resident MLP chain on native 16x16x32 f16 MFMA.
// State after each hidden layer: S[t] = 4 f16, lane(m,q) holds C rows 4q..4q+3
// of tile t, col m (= sample). Next layer's weight COLUMNS are permuted by
//   sigma: k-slot (c, q, j) -> neuron  (j<4 ? 16c+4q+j : 16(c+2)+4q+j-4)
// so the B-frag for k-chunk c is exactly cat(S[c], S[c+2]): the layer->layer
// layout transition costs ZERO instructions. Biases enter as f32 C operands.
//
// launch_bounds(256,2): 256-VGPR budget. (256,3)'s 168-cap forced scratch
// spills (R4: WRITE_SIZE 155 MB vs 8 MB of real stores). Peak live set is
// ~200 VGPRs (96 of weights + working state); 2 waves/SIMD suffice for this
// VALU-throughput-bound body.
__global__ __launch_bounds__(256, 2) void mlp_fused(
    const float* __restrict__ x,
    const float* __restrict__ W1, const float* __restrict__ b1,
    const float* __restrict__ W2, const float* __restrict__ b2,
    const float* __restrict__ W3, const float* __restrict__ b3,
    const float* __restrict__ W4, const float* __restrict__ b4,
    float* __restrict__ out, int N)
{
    const int lane = threadIdx.x & 63;
    const int m    = lane & 15;   // sample / C col / A row
    const int q    = lane >> 4;   // quad
    const float s  = INV2PI;
    const floatx4 zero4 = {0.0f, 0.0f, 0.0f, 0.0f};

    // ---------------- per-wave weight prep (reused across 8 tiles) ----------------
    // L1 A-frag (tile t): lanes q==0 hold, for out-neuron n=16t+m, k-slots
    //   [w0h, w0h, w0l, w1h, w1h, w1l, b1h, b1l]   (pairs with xa below)
    half8 w1f[4];
    #pragma unroll
    for (int t = 0; t < 4; ++t) {
        half8 v = {};
        if (q == 0) {
            const int n = 16 * t + m;
            float w0 = W1[2*n] * s, w1 = W1[2*n+1] * s, bb = b1[n] * s;
            _Float16 w0h = (_Float16)w0; float w0l = w0 - (float)w0h;
            _Float16 w1h = (_Float16)w1; float w1l = w1 - (float)w1h;
            _Float16 bh  = (_Float16)bb; float bl  = bb - (float)bh;
            v[0] = w0h; v[1] = w0h; v[2] = (_Float16)w0l;
            v[3] = w1h; v[4] = w1h; v[5] = (_Float16)w1l;
            v[6] = bh;  v[7] = (_Float16)bl;
        }
        w1f[t] = v;
    }

    // L2/L3 A-frags with sigma-permuted columns: two contiguous float4 loads.
    half8 w2f[4][2], w3f[4][2];
    floatx4 bb2[4], bb3[4];
    #pragma unroll
    for (int t = 0; t < 4; ++t) {
        const float* r2 = W2 + (16 * t + m) * 64;
        const float* r3 = W3 + (16 * t + m) * 64;
        #pragma unroll
        for (int c = 0; c < 2; ++c) {
            floatx4 lo2 = *(const floatx4*)(r2 + 16 * c + 4 * q);
            floatx4 hi2 = *(const floatx4*)(r2 + 16 * (c + 2) + 4 * q);
            floatx4 lo3 = *(const floatx4*)(r3 + 16 * c + 4 * q);
            floatx4 hi3 = *(const floatx4*)(r3 + 16 * (c + 2) + 4 * q);
            half8 v2, v3;
            #pragma unroll
            for (int j = 0; j < 4; ++j) {
                v2[j]     = (_Float16)(lo2[j] * s);
                v2[4 + j] = (_Float16)(hi2[j] * s);
                v3[j]     = (_Float16)(lo3[j] * s);
                v3[4 + j] = (_Float16)(hi3[j] * s);
            }
            w2f[t][c] = v2;
            w3f[t][c] = v3;
        }
        bb2[t] = *(const floatx4*)(b2 + 16 * t + 4 * q) * s;   // C-init: b2[16t+4q+r], exact f32
        bb3[t] = *(const floatx4*)(b3 + 16 * t + 4 * q) * s;
    }

    // L4 A-frag: only out-row m==0 real, same sigma column permutation.
    half8 w4f[2] = {half8{}, half8{}};
    if (m == 0) {
        #pragma unroll
        for (int c = 0; c < 2; ++c) {
            #pragma unroll
            for (int j = 0; j < 8; ++j) {
                int nu = (j < 4) ? (16 * c + 4 * q + j) : (16 * (c + 2) + 4 * q + j - 4);
                w4f[c][j] = (_Float16)(W4[nu] * s);
            }
        }
    }
    floatx4 a4init = zero4;
    if (q == 0) a4init[0] = b4[0] * s;       // C row 0 = (q=0, r=0)

    const int ntiles = N >> 4;
    const int nwaves = (gridDim.x * blockDim.x) >> 6;
    const int gwave  = (int)(blockIdx.x * blockDim.x + threadIdx.x) >> 6;
    const float2* __restrict__ x2 = (const float2*)x;

    int tile = gwave;
    float2 xv = x2[(tile << 4) + m];          // software-pipelined x load
    while (tile < ntiles) {
        const int nt = tile + nwaves;
        float2 xnext;
        if (nt < ntiles) xnext = x2[(nt << 4) + m];

        // L1 B-frag (lanes q==0): [xh, xl, xh, yh, yl, yh, 1, 1]
        half8 xa = {};
        if (q == 0) {
            _Float16 xh = (_Float16)xv.x; float xl = xv.x - (float)xh;
            _Float16 yh = (_Float16)xv.y; float yl = xv.y - (float)yh;
            xa[0] = xh; xa[1] = (_Float16)xl; xa[2] = xh;
            xa[3] = yh; xa[4] = (_Float16)yl; xa[5] = yh;
            xa[6] = (_Float16)1.0f; xa[7] = (_Float16)1.0f;
        }

        // ---- layer 1 ----
        half4v S[4];
        #pragma unroll
        for (int t = 0; t < 4; ++t) {
            floatx4 acc = __builtin_amdgcn_mfma_f32_16x16x32_f16(w1f[t], xa, zero4, 0, 0, 0);
            S[t] = act4(acc);
        }

        // ---- layer 2 (B chunks are free register concats) ----
        half8 B0 = cat(S[0], S[2]), B1 = cat(S[1], S[3]);
        half4v T[4];
        #pragma unroll
        for (int t = 0; t < 4; ++t) {
            floatx4 acc = __builtin_amdgcn_mfma_f32_16x16x32_f16(w2f[t][0], B0, bb2[t], 0, 0, 0);
            acc = __builtin_amdgcn_mfma_f32_16x16x32_f16(w2f[t][1], B1, acc, 0, 0, 0);
            T[t] = act4(acc);
        }

        // ---- layer 3 ----
        half8 C0 = cat(T[0], T[2]), C1 = cat(T[1], T[3]);
        #pragma unroll
        for (int t = 0; t < 4; ++t) {
            floatx4 acc = __builtin_amdgcn_mfma_f32_16x16x32_f16(w3f[t][0], C0, bb3[t], 0, 0, 0);
            acc = __builtin_amdgcn_mfma_f32_16x16x32_f16(w3f[t][1], C1, acc, 0, 0, 0);
            S[t] = act4(acc);
        }

        // ---- layer 4 + store ----
        half8 D0 = cat(S[0], S[2]), D1 = cat(S[1], S[3]);
        floatx4 a4 = __builtin_amdgcn_mfma_f32_16x16x32_f16(w4f[0], D0, a4init, 0, 0, 0);
        a4 = __builtin_amdgcn_mfma_f32_16x16x32_f16(w4f[1], D1, a4, 0, 0, 0);
        if (q == 0)
            out[(tile << 4) + m] = act_rev(a4[0]);

        xv = xnext;
        tile = nt;
    }
}

extern "C" void kernel_launch(void* const* d_in, const int* in_sizes, int n_in,
                              void* d_out, int out_size, void* d_ws, size_t ws_size,
                              hipStream_t stream) {
    const float* x  = (const float*)d_in[0];
    const float* W1 = (const float*)d_in[1];
    const float* b1 = (const float*)d_in[2];
    const float* W2 = (const float*)d_in[3];
    const float* b2 = (const float*)d_in[4];
    const float* W3 = (const float*)d_in[5];
    const float* b3 = (const float*)d_in[6];
    const float* W4 = (const float*)d_in[7];
    const float* b4 = (const float*)d_in[8];
    float* out = (float*)d_out;
    const int N = out_size;          // 2097152, divisible by 16

    // 4096 blocks x 4 waves = 16384 waves; 131072 tiles -> exactly 8 tiles/wave.
    mlp_fused<<<dim3(4096), dim3(256), 0, stream>>>(x, W1, b1, W2, b2, W3, b3, W4, b4, out, N);
}

// Round 6
// 216.414 us; speedup vs baseline: 1.0607x; 1.0607x over previous
//
#include <hip/hip_runtime.h>

typedef _Float16 half8  __attribute__((ext_vector_type(8)));
typedef _Float16 half4v __attribute__((ext_vector_type(4)));
typedef _Float16 half2v __attribute__((ext_vector_type(2)));
typedef float    floatx4 __attribute__((ext_vector_type(4)));
typedef float    float2v __attribute__((ext_vector_type(2)));

static constexpr float INV2PI = 0.15915494309189535f;  // fold rad->rev into weights
static constexpr float RLOG   = 3.82843f;

// act(a) with a in revolutions: x0 = 0.5+0.5cos -> two logistic iters.
// Algebra: x0(1-x0) = 0.25 - 0.25 c^2 = p;  out = R^2 * p * (1 - R*p).
__device__ __forceinline__ float act_rev(float a) {
    float c = __builtin_amdgcn_cosf(a);
    float qq = c * c;
    float p = __builtin_fmaf(qq, -0.25f, 0.25f);
    float w = __builtin_fmaf(p, -RLOG, 1.0f);
    return (RLOG * RLOG * p) * w;
}

// Vectorized over 4 accumulator values -> 4 packed f16 (cvt_pkrtz).
__device__ __forceinline__ half4v act4(floatx4 a) {
    float2v c0 = { __builtin_amdgcn_cosf(a[0]), __builtin_amdgcn_cosf(a[1]) };
    float2v c1 = { __builtin_amdgcn_cosf(a[2]), __builtin_amdgcn_cosf(a[3]) };
    float2v q0 = c0 * c0, q1 = c1 * c1;
    float2v p0 = __builtin_elementwise_fma(q0, (float2v)(-0.25f), (float2v)(0.25f));
    float2v p1 = __builtin_elementwise_fma(q1, (float2v)(-0.25f), (float2v)(0.25f));
    float2v w0 = __builtin_elementwise_fma(p0, (float2v)(-RLOG), (float2v)(1.0f));
    float2v w1 = __builtin_elementwise_fma(p1, (float2v)(-RLOG), (float2v)(1.0f));
    float2v u0 = p0 * (RLOG * RLOG), u1 = p1 * (RLOG * RLOG);
    float2v h0 = u0 * w0, h1 = u1 * w1;
    half2v lo = __builtin_bit_cast(half2v, __builtin_amdgcn_cvt_pkrtz(h0.x, h0.y));
    half2v hi = __builtin_bit_cast(half2v, __builtin_amdgcn_cvt_pkrtz(h1.x, h1.y));
    return __builtin_shufflevector(lo, hi, 0, 1, 2, 3);
}

__device__ __forceinline__ half8 cat(half4v a, half4v b) {
    return __builtin_shufflevector(a, b, 0, 1, 2, 3, 4, 5, 6, 7);
}

// Register-resident MLP chain on native 16x16x32 f16 MFMA.
// State after each hidden layer: S[t] = 4 f16, lane(m,q) holds C rows 4q..4q+3
// of tile t, col m (= sample). Next layer's weight COLUMNS are permuted by
//   sigma: k-slot (c, q, j) -> neuron  (j<4 ? 16c+4q+j : 16(c+2)+4q+j-4)
// so the B-frag for k-chunk c is exactly cat(S[c], S[c+2]): the layer->layer
// layout transition costs ZERO instructions. Biases enter as f32 C operands.
//
// 2-way tile jam: each wave runs TWO independent 16-sample chains per
// iteration. R5 showed 2 waves/SIMD + serial mfma->act chain = VALU fed only
// ~25% of cycles; the second in-wave chain fills the dependency stalls.
// launch_bounds(256,2): 256-reg budget ((256,3)'s 168 cap spilled in R4).
__global__ __launch_bounds__(256, 2) void mlp_fused(
    const float* __restrict__ x,
    const float* __restrict__ W1, const float* __restrict__ b1,
    const float* __restrict__ W2, const float* __restrict__ b2,
    const float* __restrict__ W3, const float* __restrict__ b3,
    const float* __restrict__ W4, const float* __restrict__ b4,
    float* __restrict__ out, int N)
{
    const int lane = threadIdx.x & 63;
    const int m    = lane & 15;   // sample / C col / A row
    const int q    = lane >> 4;   // quad
    const float s  = INV2PI;
    const floatx4 zero4 = {0.0f, 0.0f, 0.0f, 0.0f};

    // ---------------- per-wave weight prep (reused across all tiles) --------------
    // L1 A-frag (tile t): lanes q==0 hold, for out-neuron n=16t+m, k-slots
    //   [w0h, w0h, w0l, w1h, w1h, w1l, b1h, b1l]   (pairs with xa below)
    half8 w1f[4];
    #pragma unroll
    for (int t = 0; t < 4; ++t) {
        half8 v = {};
        if (q == 0) {
            const int n = 16 * t + m;
            float w0 = W1[2*n] * s, w1 = W1[2*n+1] * s, bb = b1[n] * s;
            _Float16 w0h = (_Float16)w0; float w0l = w0 - (float)w0h;
            _Float16 w1h = (_Float16)w1; float w1l = w1 - (float)w1h;
            _Float16 bh  = (_Float16)bb; float bl  = bb - (float)bh;
            v[0] = w0h; v[1] = w0h; v[2] = (_Float16)w0l;
            v[3] = w1h; v[4] = w1h; v[5] = (_Float16)w1l;
            v[6] = bh;  v[7] = (_Float16)bl;
        }
        w1f[t] = v;
    }

    // L2/L3 A-frags with sigma-permuted columns: two contiguous float4 loads.
    half8 w2f[4][2], w3f[4][2];
    floatx4 bb2[4], bb3[4];
    #pragma unroll
    for (int t = 0; t < 4; ++t) {
        const float* r2 = W2 + (16 * t + m) * 64;
        const float* r3 = W3 + (16 * t + m) * 64;
        #pragma unroll
        for (int c = 0; c < 2; ++c) {
            floatx4 lo2 = *(const floatx4*)(r2 + 16 * c + 4 * q);
            floatx4 hi2 = *(const floatx4*)(r2 + 16 * (c + 2) + 4 * q);
            floatx4 lo3 = *(const floatx4*)(r3 + 16 * c + 4 * q);
            floatx4 hi3 = *(const floatx4*)(r3 + 16 * (c + 2) + 4 * q);
            half8 v2, v3;
            #pragma unroll
            for (int j = 0; j < 4; ++j) {
                v2[j]     = (_Float16)(lo2[j] * s);
                v2[4 + j] = (_Float16)(hi2[j] * s);
                v3[j]     = (_Float16)(lo3[j] * s);
                v3[4 + j] = (_Float16)(hi3[j] * s);
            }
            w2f[t][c] = v2;
            w3f[t][c] = v3;
        }
        bb2[t] = *(const floatx4*)(b2 + 16 * t + 4 * q) * s;   // C-init: b2[16t+4q+r], exact f32
        bb3[t] = *(const floatx4*)(b3 + 16 * t + 4 * q) * s;
    }

    // L4 A-frag: only out-row m==0 real, same sigma column permutation.
    half8 w4f[2] = {half8{}, half8{}};
    if (m == 0) {
        #pragma unroll
        for (int c = 0; c < 2; ++c) {
            #pragma unroll
            for (int j = 0; j < 8; ++j) {
                int nu = (j < 4) ? (16 * c + 4 * q + j) : (16 * (c + 2) + 4 * q + j - 4);
                w4f[c][j] = (_Float16)(W4[nu] * s);
            }
        }
    }
    floatx4 a4init = zero4;
    if (q == 0) a4init[0] = b4[0] * s;       // C row 0 = (q=0, r=0)

    const int npairs = N >> 5;               // pairs of 16-row tiles
    const int nwaves = (gridDim.x * blockDim.x) >> 6;
    const int gwave  = (int)(blockIdx.x * blockDim.x + threadIdx.x) >> 6;
    const float2* __restrict__ x2 = (const float2*)x;

    int pair = gwave;
    float2 xv[2] = { x2[(pair << 5) + m], x2[(pair << 5) + 16 + m] };  // prefetched
    while (pair < npairs) {
        const int np = pair + nwaves;
        float2 xn[2];
        if (np < npairs) {
            xn[0] = x2[(np << 5) + m];
            xn[1] = x2[(np << 5) + 16 + m];
        }

        // L1 B-frags (lanes q==0): [xh, xl, xh, yh, yl, yh, 1, 1]
        half8 xa[2] = {half8{}, half8{}};
        #pragma unroll
        for (int u = 0; u < 2; ++u) {
            if (q == 0) {
                _Float16 xh = (_Float16)xv[u].x; float xl = xv[u].x - (float)xh;
                _Float16 yh = (_Float16)xv[u].y; float yl = xv[u].y - (float)yh;
                xa[u][0] = xh; xa[u][1] = (_Float16)xl; xa[u][2] = xh;
                xa[u][3] = yh; xa[u][4] = (_Float16)yl; xa[u][5] = yh;
                xa[u][6] = (_Float16)1.0f; xa[u][7] = (_Float16)1.0f;
            }
        }

        // ---- layer 1 (two independent chains interleaved) ----
        half4v S[2][4];
        #pragma unroll
        for (int t = 0; t < 4; ++t)
            #pragma unroll
            for (int u = 0; u < 2; ++u) {
                floatx4 acc = __builtin_amdgcn_mfma_f32_16x16x32_f16(w1f[t], xa[u], zero4, 0, 0, 0);
                S[u][t] = act4(acc);
            }

        // ---- layer 2 (B chunks are free register concats) ----
        half8 B0[2] = { cat(S[0][0], S[0][2]), cat(S[1][0], S[1][2]) };
        half8 B1[2] = { cat(S[0][1], S[0][3]), cat(S[1][1], S[1][3]) };
        half4v T[2][4];
        #pragma unroll
        for (int t = 0; t < 4; ++t)
            #pragma unroll
            for (int u = 0; u < 2; ++u) {
                floatx4 acc = __builtin_amdgcn_mfma_f32_16x16x32_f16(w2f[t][0], B0[u], bb2[t], 0, 0, 0);
                acc = __builtin_amdgcn_mfma_f32_16x16x32_f16(w2f[t][1], B1[u], acc, 0, 0, 0);
                T[u][t] = act4(acc);
            }

        // ---- layer 3 ----
        half8 C0[2] = { cat(T[0][0], T[0][2]), cat(T[1][0], T[1][2]) };
        half8 C1[2] = { cat(T[0][1], T[0][3]), cat(T[1][1], T[1][3]) };
        #pragma unroll
        for (int t = 0; t < 4; ++t)
            #pragma unroll
            for (int u = 0; u < 2; ++u) {
                floatx4 acc = __builtin_amdgcn_mfma_f32_16x16x32_f16(w3f[t][0], C0[u], bb3[t], 0, 0, 0);
                acc = __builtin_amdgcn_mfma_f32_16x16x32_f16(w3f[t][1], C1[u], acc, 0, 0, 0);
                S[u][t] = act4(acc);
            }

        // ---- layer 4 + store ----
        floatx4 a4[2];
        #pragma unroll
        for (int u = 0; u < 2; ++u) {
            half8 D0 = cat(S[u][0], S[u][2]), D1 = cat(S[u][1], S[u][3]);
            a4[u] = __builtin_amdgcn_mfma_f32_16x16x32_f16(w4f[0], D0, a4init, 0, 0, 0);
            a4[u] = __builtin_amdgcn_mfma_f32_16x16x32_f16(w4f[1], D1, a4[u], 0, 0, 0);
        }
        if (q == 0) {
            out[(pair << 5) + m]      = act_rev(a4[0][0]);
            out[(pair << 5) + 16 + m] = act_rev(a4[1][0]);
        }

        xv[0] = xn[0]; xv[1] = xn[1];
        pair = np;
    }
}

extern "C" void kernel_launch(void* const* d_in, const int* in_sizes, int n_in,
                              void* d_out, int out_size, void* d_ws, size_t ws_size,
                              hipStream_t stream) {
    const float* x  = (const float*)d_in[0];
    const float* W1 = (const float*)d_in[1];
    const float* b1 = (const float*)d_in[2];
    const float* W2 = (const float*)d_in[3];
    const float* b2 = (const float*)d_in[4];
    const float* W3 = (const float*)d_in[5];
    const float* b3 = (const float*)d_in[6];
    const float* W4 = (const float*)d_in[7];
    const float* b4 = (const float*)d_in[8];
    float* out = (float*)d_out;
    const int N = out_size;          // 2097152, divisible by 32

    // 4096 blocks x 4 waves = 16384 waves; 65536 tile-pairs -> 4 iterations/wave.
    mlp_fused<<<dim3(4096), dim3(256), 0, stream>>>(x, W1, b1, W2, b2, W3, b3, W4, b4, out, N);
}